// Round 3
// baseline (255.358 us; speedup 1.0000x reference)
//
#include <hip/hip_runtime.h>
#include <hip/hip_bf16.h>

// Problem constants (reference: B,S,D,K = 4, 8192, 512, 20)
#define BB 4
#define SS 8192
#define DD 512
#define KK 20
#define TT 64              // tokens per k12 block
#define CPB1 (SS / TT)     // 128 chunks/batch (fused path)
#define CPB2 64            // fallback chunks/batch

__device__ __forceinline__ float dot4(float4 a, float4 b) {
  return a.x * b.x + a.y * b.y + a.z * b.z + a.w * b.w;
}

// ---------------------------------------------------------------------------
// k12: fused attn + splat-gather partial.
//  Phase 0: stage pos into LDS; compute c2/alpha/amp in-block.
//  Phase A: attn for 64 tokens. 256 thr = 16 quads x 16 dsubs; each thread
//           owns 4 tokens (q, q+16, q+32, q+48) -> each pos LDS read feeds
//           16 token-dots (4 quads/wave broadcast x 4 tokens/thread).
//  Phase B: Mpart[blk][k][d] = sum_{s in chunk} attn[s][k] * x[s][d].
//           Thread owns float2 d-slot; x re-read (L1/L2-hot); attn from LDS.
// doM==0: skip phase B (fallback path does scatter separately).
// ---------------------------------------------------------------------------
__global__ __launch_bounds__(256) void k12_fused(
    const float* __restrict__ x, const float* __restrict__ pos,
    const float* __restrict__ log_scales, const float* __restrict__ amps,
    float* __restrict__ attn_g, float* __restrict__ Mpart, int doM) {
  __shared__ float pos_s[KK * DD];   // 40 KB
  __shared__ float attn_s[TT * KK];  // 5 KB
  __shared__ float prm_s[3 * KK];    // c2 | alpha | amp

  int tid = threadIdx.x;
  int blk = blockIdx.x;
  int b = blk >> 7;                  // blk / 128
  int c = blk & 127;
  size_t row0 = (size_t)b * SS + (size_t)c * TT;  // first token row

  // ---- stage positions (coalesced float4) ----
  for (int i = tid; i < KK * DD / 4; i += 256)
    ((float4*)pos_s)[i] = ((const float4*)pos)[i];
  __syncthreads();

  // ---- per-splat params from staged pos ----
  if (tid < KK * 8) {                // 8 lanes per k
    int k = tid >> 3, i = tid & 7;
    float a = 0.f;
    const float4* pr = (const float4*)(pos_s + k * DD);
#pragma unroll
    for (int j = 0; j < 16; ++j) {   // 16 float4 = 64 floats per lane
      float4 p = pr[i * 16 + j];
      a += dot4(p, p);
    }
    a += __shfl_xor(a, 1); a += __shfl_xor(a, 2); a += __shfl_xor(a, 4);
    if (i == 0) {
      prm_s[k] = a;                               // ||c||^2
      float s = __expf(log_scales[k]);
      prm_s[KK + k] = 0.5f / (s * s);             // alpha
      prm_s[2 * KK + k] = amps[k];                // amplitude
    }
  }
  __syncthreads();

  // ---- Phase A: dot products ----
  int q = tid >> 4;      // quad 0..15
  int dsub = tid & 15;   // 0..15
  const float* xq = x + (row0 + q) * DD;

  float acc[4][KK];
  float x2[4];
#pragma unroll
  for (int r = 0; r < 4; ++r) {
    x2[r] = 0.f;
#pragma unroll
    for (int k = 0; k < KK; ++k) acc[r][k] = 0.f;
  }

  for (int j = 0; j < 8; ++j) {
    int d0 = j * 64 + dsub * 4;
    float4 xv[4];
#pragma unroll
    for (int r = 0; r < 4; ++r) xv[r] = *(const float4*)(xq + (size_t)r * 16 * DD + d0);
#pragma unroll
    for (int r = 0; r < 4; ++r) x2[r] += dot4(xv[r], xv[r]);
#pragma unroll
    for (int k = 0; k < KK; ++k) {
      float4 p = *(const float4*)(pos_s + k * DD + d0);
#pragma unroll
      for (int r = 0; r < 4; ++r) acc[r][k] += dot4(xv[r], p);
    }
  }

  // reduce over the 16 dsub lanes (within-wave: lanes [q*16 .. q*16+15])
#pragma unroll
  for (int r = 0; r < 4; ++r) {
    x2[r] += __shfl_xor(x2[r], 1); x2[r] += __shfl_xor(x2[r], 2);
    x2[r] += __shfl_xor(x2[r], 4); x2[r] += __shfl_xor(x2[r], 8);
#pragma unroll
    for (int k = 0; k < KK; ++k) {
      float v = acc[r][k];
      v += __shfl_xor(v, 1); v += __shfl_xor(v, 2);
      v += __shfl_xor(v, 4); v += __shfl_xor(v, 8);
      acc[r][k] = v;
    }
  }

  // gauss + normalize (4 lanes/wave active; 4 tokens each)
  if (dsub == 0) {
#pragma unroll
    for (int r = 0; r < 4; ++r) {
      float g[KK];
      float sum = 0.f;
#pragma unroll
      for (int k = 0; k < KK; ++k) {
        float d2 = fmaxf(x2[r] - 2.f * acc[r][k] + prm_s[k], 0.f);
        float gk = prm_s[2 * KK + k] * __expf(-prm_s[KK + k] * d2);
        g[k] = gk;
        sum += gk;
      }
      float inv = 1.f / (sum + 1e-8f);
      float* as = attn_s + (q + r * 16) * KK;
#pragma unroll
      for (int k = 0; k < KK; ++k) as[k] = g[k] * inv;
    }
  }
  __syncthreads();

  // coalesced copy attn chunk to global
  {
    float* ag = attn_g + row0 * KK;
    for (int i = tid; i < TT * KK; i += 256) ag[i] = attn_s[i];
  }

  if (!doM) return;

  // ---- Phase B: per-chunk splat partial ----
  float2 Ml[KK];
#pragma unroll
  for (int k = 0; k < KK; ++k) Ml[k] = make_float2(0.f, 0.f);

  const float* xb = x + row0 * DD + 2 * tid;
  for (int s = 0; s < TT; ++s) {
    float2 xv = *(const float2*)(xb + (size_t)s * DD);
    const float4* ar4 = (const float4*)(attn_s + s * KK);  // broadcast reads
#pragma unroll
    for (int kk = 0; kk < KK / 4; ++kk) {
      float4 a4 = ar4[kk];
      Ml[4 * kk + 0].x += a4.x * xv.x; Ml[4 * kk + 0].y += a4.x * xv.y;
      Ml[4 * kk + 1].x += a4.y * xv.x; Ml[4 * kk + 1].y += a4.y * xv.y;
      Ml[4 * kk + 2].x += a4.z * xv.x; Ml[4 * kk + 2].y += a4.z * xv.y;
      Ml[4 * kk + 3].x += a4.w * xv.x; Ml[4 * kk + 3].y += a4.w * xv.y;
    }
  }
  float* mp = Mpart + (size_t)blk * KK * DD + 2 * tid;
#pragma unroll
  for (int k = 0; k < KK; ++k) *(float2*)(mp + (size_t)k * DD) = Ml[k];
}

// ---------------------------------------------------------------------------
// k2_fb: fallback scatter (only when ws too small for 512 Mpart slabs).
// ---------------------------------------------------------------------------
__global__ __launch_bounds__(256) void k2_fb(
    const float* __restrict__ x, const float* __restrict__ attn,
    float* __restrict__ Mpart) {
  int t = threadIdx.x;
  int c = blockIdx.x;  // 0..63
  int b = blockIdx.y;
  int s0 = c * (SS / CPB2);

  float2 Ml[KK];
#pragma unroll
  for (int k = 0; k < KK; ++k) Ml[k] = make_float2(0.f, 0.f);

  for (int s = s0; s < s0 + SS / CPB2; ++s) {
    size_t tokb = (size_t)b * SS + s;
    float2 xv = *(const float2*)(x + tokb * DD + 2 * t);
    const float4* ar4 = (const float4*)(attn + tokb * KK);
#pragma unroll
    for (int kk = 0; kk < KK / 4; ++kk) {
      float4 a4 = ar4[kk];
      Ml[4 * kk + 0].x += a4.x * xv.x; Ml[4 * kk + 0].y += a4.x * xv.y;
      Ml[4 * kk + 1].x += a4.y * xv.x; Ml[4 * kk + 1].y += a4.y * xv.y;
      Ml[4 * kk + 2].x += a4.z * xv.x; Ml[4 * kk + 2].y += a4.z * xv.y;
      Ml[4 * kk + 3].x += a4.w * xv.x; Ml[4 * kk + 3].y += a4.w * xv.y;
    }
  }
  float* base = Mpart + ((size_t)b * CPB2 + c) * KK * DD + 2 * t;
#pragma unroll
  for (int k = 0; k < KK; ++k) *(float2*)(base + (size_t)k * DD) = Ml[k];
}

// ---------------------------------------------------------------------------
// k3f: chunk-reduce + proj_v + proj_o fused. grid 80 blocks x 512 threads.
//  M[bk][e] = sum_c Mpart ; ssb[e] = sum_d M[d] w_v[e][d] ;
//  ws2[bk][e] = sum_d ssb[d] w_o[e][d]   (ssb row is block-local -> LDS)
// ---------------------------------------------------------------------------
__global__ __launch_bounds__(512) void k3f(
    const float* __restrict__ Mpart, const float* __restrict__ w_v,
    const float* __restrict__ w_o, float* __restrict__ ws2, int cpb) {
  __shared__ float m_s[DD];
  __shared__ float v_s[DD];
  int bk = blockIdx.x;
  int b = bk / KK, k = bk - b * KK;
  int e = threadIdx.x;

  const float* mp = Mpart + ((size_t)b * cpb) * KK * DD + (size_t)k * DD + e;
  float acc = 0.f;
#pragma unroll 8
  for (int c = 0; c < cpb; ++c) acc += mp[(size_t)c * KK * DD];
  m_s[e] = acc;
  __syncthreads();

  const float4* wr = (const float4*)(w_v + (size_t)e * DD);
  float a2 = 0.f;
#pragma unroll 4
  for (int j = 0; j < DD / 4; ++j) a2 += dot4(((const float4*)m_s)[j], wr[j]);
  v_s[e] = a2;
  __syncthreads();

  const float4* wr2 = (const float4*)(w_o + (size_t)e * DD);
  float a3 = 0.f;
#pragma unroll 4
  for (int j = 0; j < DD / 4; ++j) a3 += dot4(((const float4*)v_s)[j], wr2[j]);
  ws2[(size_t)bk * DD + e] = a3;
}

// ---------------------------------------------------------------------------
// k5: out[b,s,:] = sum_k attn[b,s,k] * ws2[b,k,:].  1024 blocks x 32 tokens.
// ---------------------------------------------------------------------------
__global__ __launch_bounds__(256) void k5_gather(
    const float* __restrict__ attn, const float* __restrict__ ws2,
    float* __restrict__ out) {
  __shared__ float a_s[32 * KK];
  int tid = threadIdx.x;
  int b = blockIdx.y;
  int s0 = blockIdx.x * 32;

  const float* ab = attn + ((size_t)b * SS + s0) * KK;
  for (int i = tid; i < 32 * KK; i += 256) a_s[i] = ab[i];

  float2 w[KK];
  const float* wb = ws2 + (size_t)b * KK * DD + 2 * tid;
#pragma unroll
  for (int k = 0; k < KK; ++k) w[k] = *(const float2*)(wb + (size_t)k * DD);
  __syncthreads();

  float* ob = out + ((size_t)b * SS + s0) * DD + 2 * tid;
  for (int s = 0; s < 32; ++s) {
    const float4* ar4 = (const float4*)(a_s + s * KK);
    float2 o = make_float2(0.f, 0.f);
#pragma unroll
    for (int kk = 0; kk < KK / 4; ++kk) {
      float4 a4 = ar4[kk];
      o.x += a4.x * w[4 * kk + 0].x; o.y += a4.x * w[4 * kk + 0].y;
      o.x += a4.y * w[4 * kk + 1].x; o.y += a4.y * w[4 * kk + 1].y;
      o.x += a4.z * w[4 * kk + 2].x; o.y += a4.z * w[4 * kk + 2].y;
      o.x += a4.w * w[4 * kk + 3].x; o.y += a4.w * w[4 * kk + 3].y;
    }
    *(float2*)(ob + (size_t)s * DD) = o;
  }
}

// ---------------------------------------------------------------------------
extern "C" void kernel_launch(void* const* d_in, const int* in_sizes, int n_in,
                              void* d_out, int out_size, void* d_ws, size_t ws_size,
                              hipStream_t stream) {
  const float* x   = (const float*)d_in[0];
  const float* pos = (const float*)d_in[1];
  const float* ls  = (const float*)d_in[2];
  const float* am  = (const float*)d_in[3];
  const float* w_v = (const float*)d_in[4];
  const float* w_o = (const float*)d_in[5];
  float* out = (float*)d_out;

  float* ws   = (float*)d_ws;
  float* attn = ws;                                  // B*S*K   = 655360 f
  float* ws2  = attn + (size_t)BB * SS * KK;         // B*K*D   = 40960 f
  float* Mpart = ws2 + (size_t)BB * KK * DD;         // slabs...

  size_t need_fused = ((size_t)BB * SS * KK + (size_t)BB * KK * DD +
                       (size_t)BB * CPB1 * KK * DD) * sizeof(float);  // ~23.8 MB

  if (ws_size >= need_fused) {
    k12_fused<<<BB * SS / TT, 256, 0, stream>>>(x, pos, ls, am, attn, Mpart, 1);
    k3f<<<BB * KK, 512, 0, stream>>>(Mpart, w_v, w_o, ws2, CPB1);
  } else {
    k12_fused<<<BB * SS / TT, 256, 0, stream>>>(x, pos, ls, am, attn, Mpart, 0);
    k2_fb<<<dim3(CPB2, BB), 256, 0, stream>>>(x, attn, Mpart);
    k3f<<<BB * KK, 512, 0, stream>>>(Mpart, w_v, w_o, ws2, CPB2);
  }
  k5_gather<<<dim3(SS / 32, BB), 256, 0, stream>>>(attn, ws2, out);
}